// Round 12
// baseline (149.094 us; speedup 1.0000x reference)
//
#include <hip/hip_runtime.h>

typedef unsigned short u16;
typedef unsigned int u32;

#define N_PTS 65536
#define KK 27
#define CIN 4
#define CC 32
#define NWIN 2048
#define CAP 32
#define NH 2
#define HD 16

typedef short s16x8 __attribute__((ext_vector_type(8)));
typedef float f32x4 __attribute__((ext_vector_type(4)));

__device__ __forceinline__ float bf2f(u16 h) { return __uint_as_float(((u32)h) << 16); }
__device__ __forceinline__ u16 f2bf(float f) {
    u32 u = __float_as_uint(f);
    u32 r = (u + 0x7FFFu + ((u >> 16) & 1u)) >> 16;
    return (u16)r;
}
__device__ __forceinline__ float ldany(const void* src, int i, bool isbf) {
    return isbf ? bf2f(((const u16*)src)[i]) : ((const float*)src)[i];
}
__device__ __forceinline__ u16 ldbf(const void* src, int i, bool isbf) {
    return isbf ? ((const u16*)src)[i] : f2bf(((const float*)src)[i]);
}

// ---- single prep kernel; per-block inline dtype detection ----
struct Ptrs { const void* p[24]; };

__global__ __launch_bounds__(256) void prep_all(
    Ptrs in,
    u16* __restrict__ fbf,
    u16* __restrict__ WpA1, u16* __restrict__ WpA2,
    u16* __restrict__ WpB1, u16* __restrict__ WpB2, u16* __restrict__ WpIN,
    u16* __restrict__ wqkvB, u16* __restrict__ wprojB,
    u16* __restrict__ tqB, u16* __restrict__ tkB, u16* __restrict__ tvb,
    float* __restrict__ Pf)
{
    // inline detect: 256 words of feats; bf16 low-half exponent in [100,140]
    __shared__ int red[256];
    int t = threadIdx.x;
    {
        u32 wd = ((const u32*)in.p[0])[t];
        u32 e = (wd >> 7) & 0xFFu;
        red[t] = (e >= 100 && e <= 140) ? 1 : 0;
    }
    __syncthreads();
    for (int s = 128; s > 0; s >>= 1) {
        if (t < s) red[t] += red[t + s];
        __syncthreads();
    }
    bool isbf = red[0] > 128;

    int seg = blockIdx.y;
    int i = blockIdx.x * 256 + t;
    if (seg == 0) {
        if (i < N_PTS * CIN) fbf[i] = ldbf(in.p[0], i, isbf);
        return;
    }
    if (seg <= 4) {
        if (i < 27648) {
            int e = i & 7, l = (i >> 3) & 63, dt = (i >> 9) & 1, k = i >> 10;
            const void* src = in.p[seg == 1 ? 7 : seg == 2 ? 10 : seg == 3 ? 13 : 16];
            u16* dst = seg == 1 ? WpA1 : seg == 2 ? WpA2 : seg == 3 ? WpB1 : WpB2;
            dst[i] = ldbf(src, k * 1024 + ((l >> 4) * 8 + e) * 32 + dt * 16 + (l & 15), isbf);
        }
        return;
    }
    if (seg == 5) {
        if (i < 4096) {
            int e = i & 7, l = (i >> 3) & 63, dt = (i >> 9) & 1, kk = i >> 10;
            int g = kk * 32 + (l >> 4) * 8 + e;
            int tp = g >> 2, c = g & 3;
            WpIN[i] = (tp < KK) ? ldbf(in.p[4], tp * 128 + c * 32 + dt * 16 + (l & 15), isbf) : (u16)0;
        }
        return;
    }
    if (seg == 6) {
        if (i < 3072) {
            int e = i & 7, l = (i >> 3) & 63, n = i >> 9;
            wqkvB[i] = ldbf(in.p[17], ((l >> 4) * 8 + e) * 96 + n * 16 + (l & 15), isbf);
        } else if (i < 4096) {
            int o2 = i - 3072;
            int e = o2 & 7, l = (o2 >> 3) & 63, n = o2 >> 9;
            wprojB[o2] = ldbf(in.p[19], ((l >> 4) * 8 + e) * 32 + n * 16 + (l & 15), isbf);
        }
        return;
    }
    if (seg == 7) {
        if (i < 9216) {
            int e = i & 7, l = (i >> 3) & 63, nn = i >> 9;
            int n = nn % 9, h = nn / 9, lr = l & 15, lg = l >> 4;
            int k = lg * 8 + e;
            tqB[i] = (k < HD) ? ldbf(in.p[21], (n * 16 + lr) * 32 + h * 16 + k, isbf) : (u16)0;
        } else if (i < 18432) {
            int o2 = i - 9216;
            int e = o2 & 7, l = (o2 >> 3) & 63, nn = o2 >> 9;
            int n = nn % 9, h = nn / 9, lr = l & 15, lg = l >> 4;
            int k = lg * 8 + e;
            tkB[o2] = (k < HD) ? ldbf(in.p[22], (n * 16 + lr) * 32 + h * 16 + k, isbf) : (u16)0;
        } else if (i < 23040) {
            int o2 = i - 18432;
            tvb[o2] = ldbf(in.p[23], o2, isbf);
        }
        return;
    }
    // seg 8: GB(8x32) | bqkv(96)@256 | bproj(32)@352
    if (i < 256) {
        const int srcs[8] = {5, 6, 8, 9, 11, 12, 14, 15};
        Pf[i] = ldany(in.p[srcs[i >> 5]], i & 31, isbf);
    } else if (i < 352) {
        Pf[i] = ldany(in.p[18], i - 256, isbf);
    } else if (i < 384) {
        Pf[i] = ldany(in.p[20], i - 352, isbf);
    }
}

// ---- MFMA input conv: batch-load phase then compute phase ----
__global__ __launch_bounds__(256) void convin_mfma(
    const u16* __restrict__ fb, const int* __restrict__ pairs,
    const u16* __restrict__ Wp, const float* __restrict__ gb,
    float* __restrict__ xbuf, u16* __restrict__ act_out)
{
    int t = threadIdx.x;
    int wv = t >> 6, l = t & 63;
    int lr = l & 15, lg = l >> 4;
    int p0 = (blockIdx.x * 4 + wv) * 16;
    int rowaddr = p0 + lr;

    int ia[4], ib[4];
    u32 ma[4], mb[4];
#pragma unroll
    for (int kk = 0; kk < 4; kk++) {
        int t0 = kk * 8 + lg * 2;
        int ta = t0 < 26 ? t0 : 26;
        int tb = (t0 + 1) < 26 ? (t0 + 1) : 26;
        ia[kk] = pairs[ta * N_PTS + rowaddr];
        ib[kk] = pairs[tb * N_PTS + rowaddr];
        ma[kk] = (t0 < KK && ia[kk] >= 0) ? 0xFFFFFFFFu : 0u;
        mb[kk] = (t0 + 1 < KK && ib[kk] >= 0) ? 0xFFFFFFFFu : 0u;
    }
    uint2 qa[4], qb[4];
    s16x8 b0[4], b1[4];
#pragma unroll
    for (int kk = 0; kk < 4; kk++) {
        qa[kk] = *(const uint2*)(fb + (long)(ia[kk] < 0 ? 0 : ia[kk]) * CIN);
        qb[kk] = *(const uint2*)(fb + (long)(ib[kk] < 0 ? 0 : ib[kk]) * CIN);
        const s16x8* wb = (const s16x8*)Wp + kk * 128 + l;
        b0[kk] = wb[0];
        b1[kk] = wb[64];
    }

    f32x4 acc0 = {0.f, 0.f, 0.f, 0.f}, acc1 = {0.f, 0.f, 0.f, 0.f};
#pragma unroll
    for (int kk = 0; kk < 4; kk++) {
        union { uint4 q; s16x8 v; } a;
        a.q = make_uint4(qa[kk].x & ma[kk], qa[kk].y & ma[kk],
                         qb[kk].x & mb[kk], qb[kk].y & mb[kk]);
        acc0 = __builtin_amdgcn_mfma_f32_16x16x32_bf16(a.v, b0[kk], acc0, 0, 0, 0);
        acc1 = __builtin_amdgcn_mfma_f32_16x16x32_bf16(a.v, b1[kk], acc1, 0, 0, 0);
    }
    float g0 = gb[lr], b0v = gb[32 + lr], g1 = gb[16 + lr], b1v = gb[48 + lr];
#pragma unroll
    for (int r = 0; r < 4; r++) {
        int row = p0 + lg * 4 + r;
        long o0 = (long)row * 32 + lr, o1 = o0 + 16;
        float v0 = acc0[r], v1 = acc1[r];
        xbuf[o0] = v0; xbuf[o1] = v1;
        act_out[o0] = f2bf(fmaxf(fmaf(v0, g0, b0v), 0.f));
        act_out[o1] = f2bf(fmaxf(fmaf(v1, g1, b1v), 0.f));
    }
}

// ---- MFMA 32->32 gather conv; 26 taps in 52KB LDS (3 blocks/CU), tap 26 from L2 ----
// mask kept as 27-bit word (no idx[27] array) to stay under 85 VGPR for 6 waves/SIMD.
// M: bit0 READ_X, bit1 WRITE_X, bit2 WRITE_ACT
template <int M>
__global__ __launch_bounds__(512, 6) void conv32_lds(
    const u16* __restrict__ act_in, const int* __restrict__ pairs,
    const u16* __restrict__ Wp, const float* __restrict__ gb,
    float* __restrict__ xbuf, u16* __restrict__ act_out)
{
    __shared__ u16 wlds[26 * 1024];   // 53248 B
    int t = threadIdx.x;
    int wv = t >> 6, l = t & 63;
    int lr = l & 15, lg = l >> 4;

    // cooperative stage of taps 0..25: 3328 uint4
    {
        const uint4* src = (const uint4*)Wp;
        uint4* dst = (uint4*)wlds;
#pragma unroll
        for (int q = 0; q < 7; q++) {
            int e = q * 512 + t;
            if (e < 3328) dst[e] = src[e];
        }
    }
    __syncthreads();

    float g0 = 0.f, b0v = 0.f, g1 = 0.f, b1v = 0.f;
    if (M & 4) { g0 = gb[lr]; b0v = gb[32 + lr]; g1 = gb[16 + lr]; b1v = gb[48 + lr]; }

#pragma unroll
    for (int tile = 0; tile < 2; tile++) {
        int p0 = ((blockIdx.x * 8 + wv) * 2 + tile) * 16;
        int rowaddr = p0 + lr;

        u32 mbits = 0;
        uint4 qr[8];
#pragma unroll
        for (int k = 0; k < KK; k++) {
            int id = pairs[k * N_PTS + rowaddr];
            mbits |= (id >= 0 ? 1u : 0u) << k;
            if (k < 8) qr[k] = *(const uint4*)(act_in + (long)(id < 0 ? 0 : id) * CC + lg * 8);
        }

        f32x4 acc0 = {0.f, 0.f, 0.f, 0.f}, acc1 = {0.f, 0.f, 0.f, 0.f};
#pragma unroll
        for (int k = 0; k < KK; k++) {
            int s = k & 7;
            uint4 q = qr[s];
            if (k + 8 < KK) {
                int kn = k + 8;
                int id = pairs[kn * N_PTS + rowaddr];
                qr[s] = *(const uint4*)(act_in + (long)(id < 0 ? 0 : id) * CC + lg * 8);
            }
            u32 msk = (mbits >> k) & 1u ? 0xFFFFFFFFu : 0u;
            q.x &= msk; q.y &= msk; q.z &= msk; q.w &= msk;
            union { uint4 q; s16x8 v; } a;
            a.q = q;
            const s16x8* wb = (k < 26) ? ((const s16x8*)wlds + k * 128 + l)
                                       : ((const s16x8*)Wp + 26 * 128 + l);
            s16x8 w0 = wb[0];
            s16x8 w1 = wb[64];
            acc0 = __builtin_amdgcn_mfma_f32_16x16x32_bf16(a.v, w0, acc0, 0, 0, 0);
            acc1 = __builtin_amdgcn_mfma_f32_16x16x32_bf16(a.v, w1, acc1, 0, 0, 0);
        }
#pragma unroll
        for (int r = 0; r < 4; r++) {
            int row = p0 + lg * 4 + r;
            long o0 = (long)row * 32 + lr, o1 = o0 + 16;
            float v0 = acc0[r], v1 = acc1[r];
            if (M & 1) { v0 += xbuf[o0]; v1 += xbuf[o1]; }
            if (M & 2) { xbuf[o0] = v0; xbuf[o1] = v1; }
            if (M & 4) {
                act_out[o0] = f2bf(fmaxf(fmaf(v0, g0, b0v), 0.f));
                act_out[o1] = f2bf(fmaxf(fmaf(v1, g1, b1v), 0.f));
            }
        }
    }
}

// ---- attention v7: 1 window per 512-thread block, 8-wave roles, 39.4KB LDS ----
#define A5_RIDX 0
#define A5_QSB  4096
#define A5_KSB  6656
#define A5_VST  9216
#define A5_SC   11776
#define A5_BQ   20992
#define A5_BK   30208
#define A5_SIZE 39424

__global__ __launch_bounds__(512, 8) void attn7_kernel(
    const float* __restrict__ x, const int* __restrict__ win_idx,
    const int* __restrict__ rel_idx,
    const u16* __restrict__ wqkvB, const u16* __restrict__ wprojB,
    const float* __restrict__ Pf,
    const u16* __restrict__ tqB, const u16* __restrict__ tkB, const u16* __restrict__ tvb,
    float* __restrict__ out)
{
    __shared__ __align__(16) char arena[A5_SIZE];
    int*   ridx = (int*)(arena + A5_RIDX);
    u16*   qsb  = (u16*)(arena + A5_QSB);
    u16*   ksb  = (u16*)(arena + A5_KSB);
    u16*   vsT  = (u16*)(arena + A5_VST);
    float* sc   = (float*)(arena + A5_SC);
    u16*   psb  = (u16*)(arena + A5_SC);
    u16*   Bq   = (u16*)(arena + A5_BQ);
    u16*   Bk   = (u16*)(arena + A5_BK);
    float* ot   = (float*)(arena + A5_BQ);

    int w = blockIdx.x, t = threadIdx.x;
    int wv = t >> 6, l = t & 63, lr = l & 15, lg = l >> 4;

    if (t < 256) {
        int4 r4 = *(const int4*)(rel_idx + (long)w * 1024 + t * 4);
        *(int4*)(ridx + t * 4) = r4;
    }
    // qkv: 12 MFMA over 8 waves
    {
        const float* bqkv = Pf + 256;
        for (int pi = wv; pi < 12; pi += 8) {
            int n = pi >> 1, m = pi & 1;
            int gi = win_idx[w * 32 + m * 16 + lr];
            const float* xr = x + (long)gi * 32 + lg * 8;
            float4 x0 = *(const float4*)(xr);
            float4 x1 = *(const float4*)(xr + 4);
            union { s16x8 v; u16 h[8]; } a;
            a.h[0] = f2bf(x0.x); a.h[1] = f2bf(x0.y); a.h[2] = f2bf(x0.z); a.h[3] = f2bf(x0.w);
            a.h[4] = f2bf(x1.x); a.h[5] = f2bf(x1.y); a.h[6] = f2bf(x1.z); a.h[7] = f2bf(x1.w);
            s16x8 b = *(const s16x8*)(wqkvB + ((n * 64 + l) << 3));
            f32x4 acc = {0.f, 0.f, 0.f, 0.f};
            acc = __builtin_amdgcn_mfma_f32_16x16x32_bf16(a.v, b, acc, 0, 0, 0);
            int tt = n * 16 + lr;
            float bias = bqkv[tt];
#pragma unroll
            for (int r = 0; r < 4; r++) {
                int tok = m * 16 + lg * 4 + r;
                float v = acc[r] + bias;
                if (tt < 32)      qsb[tok * 40 + tt] = f2bf(v * 0.25f);   // HD^-0.5
                else if (tt < 64) ksb[tok * 40 + (tt - 32)] = f2bf(v);
                else              vsT[(tt - 64) * 40 + tok] = f2bf(v);
            }
        }
    }
    __syncthreads();

    // per-h rel-bias: 8-wave roles (tb, m, n-half), 4-5 MFMA each
    for (int h = 0; h < NH; h++) {
        {
            int tb = (wv >> 2) & 1, m = (wv >> 1) & 1, nh = wv & 1;
            const u16* src = tb ? ksb : qsb;
            const u16* tab = tb ? tkB : tqB;
            u16* dst = tb ? Bk : Bq;
            s16x8 a = {0, 0, 0, 0, 0, 0, 0, 0};
            if (lg < 2) a = *(const s16x8*)(src + (m * 16 + lr) * 40 + h * 16 + lg * 8);
            int n0 = nh * 5, n1 = nh ? 9 : 5;
            for (int n = n0; n < n1; n++) {
                s16x8 b = *(const s16x8*)(tab + (((h * 9 + n) * 64 + l) << 3));
                f32x4 acc = {0.f, 0.f, 0.f, 0.f};
                acc = __builtin_amdgcn_mfma_f32_16x16x32_bf16(a, b, acc, 0, 0, 0);
#pragma unroll
                for (int r = 0; r < 4; r++)
                    dst[(m * 16 + lg * 4 + r) * 144 + n * 16 + lr] = f2bf(acc[r]);
            }
        }
        __syncthreads();
        for (int e = t; e < 1024; e += 512) {
            int i = e >> 5, j = e & 31, r = ridx[e];
            sc[h * 1152 + i * 36 + j] = bf2f(Bq[i * 144 + r]) + bf2f(Bk[j * 144 + r]);
        }
        __syncthreads();
    }

    // qk^T: 8 MFMA, exactly one per wave
    {
        int h = wv >> 2, m = (wv >> 1) & 1, n = wv & 1;
        s16x8 a = {0, 0, 0, 0, 0, 0, 0, 0}, b = {0, 0, 0, 0, 0, 0, 0, 0};
        if (lg < 2) {
            a = *(const s16x8*)(qsb + (m * 16 + lr) * 40 + h * 16 + lg * 8);
            b = *(const s16x8*)(ksb + (n * 16 + lr) * 40 + h * 16 + lg * 8);
        }
        f32x4 acc = {0.f, 0.f, 0.f, 0.f};
        acc = __builtin_amdgcn_mfma_f32_16x16x32_bf16(a, b, acc, 0, 0, 0);
#pragma unroll
        for (int r = 0; r < 4; r++)
            sc[h * 1152 + (m * 16 + lg * 4 + r) * 36 + n * 16 + lr] += acc[r];
    }
    __syncthreads();

    // softmax: 8 lanes per row (64 rows), 4 elems each
    {
        int rr = t >> 3, sub = t & 7;
        int h = rr >> 5, i = rr & 31, j0 = sub * 4;
        const float* srow = sc + h * 1152 + i * 36 + j0;
        float pv[4];
        float m_ = -1e30f;
#pragma unroll
        for (int jj = 0; jj < 4; jj++) { pv[jj] = srow[jj]; m_ = fmaxf(m_, pv[jj]); }
        m_ = fmaxf(m_, __shfl_xor(m_, 1));
        m_ = fmaxf(m_, __shfl_xor(m_, 2));
        m_ = fmaxf(m_, __shfl_xor(m_, 4));
        float sum = 0.f;
#pragma unroll
        for (int jj = 0; jj < 4; jj++) { pv[jj] = __expf(pv[jj] - m_); sum += pv[jj]; }
        sum += __shfl_xor(sum, 1);
        sum += __shfl_xor(sum, 2);
        sum += __shfl_xor(sum, 4);
        float inv = 1.f / sum;
        __syncthreads();   // all sc reads complete before psb alias overwrite
        u16* prow = psb + h * 1280 + i * 40 + j0;
#pragma unroll
        for (int jj = 0; jj < 4; jj++) prow[jj] = f2bf(pv[jj] * inv);
    }
    __syncthreads();

    // tv gather: one (i,hp) per thread
    {
        int i = t >> 4, hp = t & 15, h = hp >> 3;
        const u16* prow = psb + h * 1280 + i * 40;
        const int* rrow = ridx + i * 32;
        float a0 = 0.f, a1 = 0.f;
#pragma unroll 8
        for (int j = 0; j < CAP; j++) {
            int r = rrow[j];
            float p = bf2f(prow[j]);
            u32 tv2 = *(const u32*)(tvb + r * 32 + hp * 2);
            a0 = fmaf(p, __uint_as_float(tv2 << 16), a0);
            a1 = fmaf(p, __uint_as_float(tv2 & 0xffff0000u), a1);
        }
        ot[i * 36 + hp * 2] = a0;
        ot[i * 36 + hp * 2 + 1] = a1;
    }
    __syncthreads();

    // PV: 4 MFMA (waves 0-3), accumulate into ot
    if (wv < 4) {
        int h = wv >> 1, m = wv & 1;
        s16x8 a = *(const s16x8*)(psb + h * 1280 + (m * 16 + lr) * 40 + lg * 8);
        s16x8 b = *(const s16x8*)(vsT + (h * 16 + lr) * 40 + lg * 8);
        f32x4 acc = {0.f, 0.f, 0.f, 0.f};
        acc = __builtin_amdgcn_mfma_f32_16x16x32_bf16(a, b, acc, 0, 0, 0);
#pragma unroll
        for (int r = 0; r < 4; r++)
            ot[(m * 16 + lg * 4 + r) * 36 + h * 16 + lr] += acc[r];
    }
    __syncthreads();

    // proj: 4 MFMA (waves 4-7) + residual + scatter
    if (wv >= 4) {
        int m = (wv >> 1) & 1, n = wv & 1;
        union { s16x8 v; u16 h[8]; } a;
        const float* orow = ot + (m * 16 + lr) * 36 + lg * 8;
#pragma unroll
        for (int e = 0; e < 8; e++) a.h[e] = f2bf(orow[e]);
        s16x8 b = *(const s16x8*)(wprojB + ((n * 64 + l) << 3));
        f32x4 acc = {0.f, 0.f, 0.f, 0.f};
        acc = __builtin_amdgcn_mfma_f32_16x16x32_bf16(a.v, b, acc, 0, 0, 0);
        int c = n * 16 + lr;
        float bb = Pf[352 + c];
#pragma unroll
        for (int r = 0; r < 4; r++) {
            int tok = m * 16 + lg * 4 + r;
            int gi = win_idx[w * 32 + tok];
            out[(long)gi * 32 + c] = x[(long)gi * 32 + c] + bb + acc[r];
        }
    }
}

// ---- ws byte offsets ----
#define B_PF     0
#define B_ACTA   2048
#define B_ACTB   4196352
#define B_FEATS  8390656
#define B_WA1    8914944
#define B_WA2    8970240
#define B_WB1    9025536
#define B_WB2    9080832
#define B_WIN    9136128
#define B_WQKVB  9144320
#define B_WPROJB 9150464
#define B_TQBF   9152512
#define B_TKBF   9170944
#define B_TVBF   9189376

extern "C" void kernel_launch(void* const* d_in, const int* in_sizes, int n_in,
                              void* d_out, int out_size, void* d_ws, size_t ws_size,
                              hipStream_t stream) {
    const void* feats  = d_in[0];
    const int* pairs   = (const int*)d_in[1];
    const int* win_idx = (const int*)d_in[2];
    const int* rel_idx = (const int*)d_in[3];
    (void)feats;

    char* wsb = (char*)d_ws;
    float* Pf = (float*)(wsb + B_PF);
    u16* actA = (u16*)(wsb + B_ACTA);
    u16* actB = (u16*)(wsb + B_ACTB);
    u16* fbf  = (u16*)(wsb + B_FEATS);
    u16* WpA1 = (u16*)(wsb + B_WA1);
    u16* WpA2 = (u16*)(wsb + B_WA2);
    u16* WpB1 = (u16*)(wsb + B_WB1);
    u16* WpB2 = (u16*)(wsb + B_WB2);
    u16* WpIN = (u16*)(wsb + B_WIN);
    u16* wqkvB  = (u16*)(wsb + B_WQKVB);
    u16* wprojB = (u16*)(wsb + B_WPROJB);
    u16* tqB = (u16*)(wsb + B_TQBF);
    u16* tkB = (u16*)(wsb + B_TKBF);
    u16* tvb = (u16*)(wsb + B_TVBF);
    float* X  = (float*)d_out;

    Ptrs pp;
    for (int i = 0; i < 24; i++) pp.p[i] = d_in[i];
    prep_all<<<dim3(1024, 9), 256, 0, stream>>>(pp, fbf,
                                                WpA1, WpA2, WpB1, WpB2, WpIN,
                                                wqkvB, wprojB, tqB, tkB, tvb, Pf);

    convin_mfma<<<1024, 256, 0, stream>>>(fbf, pairs, WpIN, Pf + 0, X, actA);
    conv32_lds<4><<<256, 512, 0, stream>>>(actA, pairs, WpA1, Pf + 64,  X, actB);
    conv32_lds<7><<<256, 512, 0, stream>>>(actB, pairs, WpA2, Pf + 128, X, actA);
    conv32_lds<4><<<256, 512, 0, stream>>>(actA, pairs, WpB1, Pf + 192, X, actB);
    conv32_lds<3><<<256, 512, 0, stream>>>(actB, pairs, WpB2, Pf, X, actA);

    attn7_kernel<<<NWIN, 512, 0, stream>>>(X, win_idx, rel_idx,
                                           wqkvB, wprojB, Pf,
                                           tqB, tkB, tvb, X);
}

// Round 13
// 111.858 us; speedup vs baseline: 1.3329x; 1.3329x over previous
//
#include <hip/hip_runtime.h>

typedef unsigned short u16;
typedef unsigned int u32;

#define N_PTS 65536
#define KK 27
#define CIN 4
#define CC 32
#define NWIN 2048
#define CAP 32
#define NH 2
#define HD 16

typedef short s16x8 __attribute__((ext_vector_type(8)));
typedef float f32x4 __attribute__((ext_vector_type(4)));

__device__ __forceinline__ float bf2f(u16 h) { return __uint_as_float(((u32)h) << 16); }
__device__ __forceinline__ u16 f2bf(float f) {
    u32 u = __float_as_uint(f);
    u32 r = (u + 0x7FFFu + ((u >> 16) & 1u)) >> 16;
    return (u16)r;
}
__device__ __forceinline__ float ldany(const void* src, int i, bool isbf) {
    return isbf ? bf2f(((const u16*)src)[i]) : ((const float*)src)[i];
}
__device__ __forceinline__ u16 ldbf(const void* src, int i, bool isbf) {
    return isbf ? ((const u16*)src)[i] : f2bf(((const float*)src)[i]);
}

// ---- single prep kernel; per-block inline dtype detection ----
struct Ptrs { const void* p[24]; };

__global__ __launch_bounds__(256) void prep_all(
    Ptrs in,
    u16* __restrict__ fbf,
    u16* __restrict__ WpA1, u16* __restrict__ WpA2,
    u16* __restrict__ WpB1, u16* __restrict__ WpB2, u16* __restrict__ WpIN,
    u16* __restrict__ wqkvB, u16* __restrict__ wprojB,
    u16* __restrict__ tqB, u16* __restrict__ tkB, u16* __restrict__ tvb,
    float* __restrict__ Pf)
{
    // inline detect: 256 words of feats; bf16 low-half exponent in [100,140]
    __shared__ int red[256];
    int t = threadIdx.x;
    {
        u32 wd = ((const u32*)in.p[0])[t];
        u32 e = (wd >> 7) & 0xFFu;
        red[t] = (e >= 100 && e <= 140) ? 1 : 0;
    }
    __syncthreads();
    for (int s = 128; s > 0; s >>= 1) {
        if (t < s) red[t] += red[t + s];
        __syncthreads();
    }
    bool isbf = red[0] > 128;

    int seg = blockIdx.y;
    int i = blockIdx.x * 256 + t;
    if (seg == 0) {
        if (i < N_PTS * CIN) fbf[i] = ldbf(in.p[0], i, isbf);
        return;
    }
    if (seg <= 4) {
        if (i < 27648) {
            int e = i & 7, l = (i >> 3) & 63, dt = (i >> 9) & 1, k = i >> 10;
            const void* src = in.p[seg == 1 ? 7 : seg == 2 ? 10 : seg == 3 ? 13 : 16];
            u16* dst = seg == 1 ? WpA1 : seg == 2 ? WpA2 : seg == 3 ? WpB1 : WpB2;
            dst[i] = ldbf(src, k * 1024 + ((l >> 4) * 8 + e) * 32 + dt * 16 + (l & 15), isbf);
        }
        return;
    }
    if (seg == 5) {
        if (i < 4096) {
            int e = i & 7, l = (i >> 3) & 63, dt = (i >> 9) & 1, kk = i >> 10;
            int g = kk * 32 + (l >> 4) * 8 + e;
            int tp = g >> 2, c = g & 3;
            WpIN[i] = (tp < KK) ? ldbf(in.p[4], tp * 128 + c * 32 + dt * 16 + (l & 15), isbf) : (u16)0;
        }
        return;
    }
    if (seg == 6) {
        if (i < 3072) {
            int e = i & 7, l = (i >> 3) & 63, n = i >> 9;
            wqkvB[i] = ldbf(in.p[17], ((l >> 4) * 8 + e) * 96 + n * 16 + (l & 15), isbf);
        } else if (i < 4096) {
            int o2 = i - 3072;
            int e = o2 & 7, l = (o2 >> 3) & 63, n = o2 >> 9;
            wprojB[o2] = ldbf(in.p[19], ((l >> 4) * 8 + e) * 32 + n * 16 + (l & 15), isbf);
        }
        return;
    }
    if (seg == 7) {
        if (i < 9216) {
            int e = i & 7, l = (i >> 3) & 63, nn = i >> 9;
            int n = nn % 9, h = nn / 9, lr = l & 15, lg = l >> 4;
            int k = lg * 8 + e;
            tqB[i] = (k < HD) ? ldbf(in.p[21], (n * 16 + lr) * 32 + h * 16 + k, isbf) : (u16)0;
        } else if (i < 18432) {
            int o2 = i - 9216;
            int e = o2 & 7, l = (o2 >> 3) & 63, nn = o2 >> 9;
            int n = nn % 9, h = nn / 9, lr = l & 15, lg = l >> 4;
            int k = lg * 8 + e;
            tkB[o2] = (k < HD) ? ldbf(in.p[22], (n * 16 + lr) * 32 + h * 16 + k, isbf) : (u16)0;
        } else if (i < 23040) {
            int o2 = i - 18432;
            tvb[o2] = ldbf(in.p[23], o2, isbf);
        }
        return;
    }
    // seg 8: GB(8x32) | bqkv(96)@256 | bproj(32)@352
    if (i < 256) {
        const int srcs[8] = {5, 6, 8, 9, 11, 12, 14, 15};
        Pf[i] = ldany(in.p[srcs[i >> 5]], i & 31, isbf);
    } else if (i < 352) {
        Pf[i] = ldany(in.p[18], i - 256, isbf);
    } else if (i < 384) {
        Pf[i] = ldany(in.p[20], i - 352, isbf);
    }
}

// ---- MFMA input conv: batch-load phase then compute phase ----
__global__ __launch_bounds__(256) void convin_mfma(
    const u16* __restrict__ fb, const int* __restrict__ pairs,
    const u16* __restrict__ Wp, const float* __restrict__ gb,
    float* __restrict__ xbuf, u16* __restrict__ act_out)
{
    int t = threadIdx.x;
    int wv = t >> 6, l = t & 63;
    int lr = l & 15, lg = l >> 4;
    int p0 = (blockIdx.x * 4 + wv) * 16;
    int rowaddr = p0 + lr;

    int ia[4], ib[4];
    u32 ma[4], mb[4];
#pragma unroll
    for (int kk = 0; kk < 4; kk++) {
        int t0 = kk * 8 + lg * 2;
        int ta = t0 < 26 ? t0 : 26;
        int tb = (t0 + 1) < 26 ? (t0 + 1) : 26;
        ia[kk] = pairs[ta * N_PTS + rowaddr];
        ib[kk] = pairs[tb * N_PTS + rowaddr];
        ma[kk] = (t0 < KK && ia[kk] >= 0) ? 0xFFFFFFFFu : 0u;
        mb[kk] = (t0 + 1 < KK && ib[kk] >= 0) ? 0xFFFFFFFFu : 0u;
    }
    uint2 qa[4], qb[4];
    s16x8 b0[4], b1[4];
#pragma unroll
    for (int kk = 0; kk < 4; kk++) {
        qa[kk] = *(const uint2*)(fb + (long)(ia[kk] < 0 ? 0 : ia[kk]) * CIN);
        qb[kk] = *(const uint2*)(fb + (long)(ib[kk] < 0 ? 0 : ib[kk]) * CIN);
        const s16x8* wb = (const s16x8*)Wp + kk * 128 + l;
        b0[kk] = wb[0];
        b1[kk] = wb[64];
    }

    f32x4 acc0 = {0.f, 0.f, 0.f, 0.f}, acc1 = {0.f, 0.f, 0.f, 0.f};
#pragma unroll
    for (int kk = 0; kk < 4; kk++) {
        union { uint4 q; s16x8 v; } a;
        a.q = make_uint4(qa[kk].x & ma[kk], qa[kk].y & ma[kk],
                         qb[kk].x & mb[kk], qb[kk].y & mb[kk]);
        acc0 = __builtin_amdgcn_mfma_f32_16x16x32_bf16(a.v, b0[kk], acc0, 0, 0, 0);
        acc1 = __builtin_amdgcn_mfma_f32_16x16x32_bf16(a.v, b1[kk], acc1, 0, 0, 0);
    }
    float g0 = gb[lr], b0v = gb[32 + lr], g1 = gb[16 + lr], b1v = gb[48 + lr];
#pragma unroll
    for (int r = 0; r < 4; r++) {
        int row = p0 + lg * 4 + r;
        long o0 = (long)row * 32 + lr, o1 = o0 + 16;
        float v0 = acc0[r], v1 = acc1[r];
        xbuf[o0] = v0; xbuf[o1] = v1;
        act_out[o0] = f2bf(fmaxf(fmaf(v0, g0, b0v), 0.f));
        act_out[o1] = f2bf(fmaxf(fmaf(v1, g1, b1v), 0.f));
    }
}

// ---- MFMA 32->32 gather conv; round-11 config: 27 taps in LDS, 512 thr, 4 waves/SIMD ----
// M: bit0 READ_X, bit1 WRITE_X, bit2 WRITE_ACT
template <int M>
__global__ __launch_bounds__(512, 4) void conv32_lds(
    const u16* __restrict__ act_in, const int* __restrict__ pairs,
    const u16* __restrict__ Wp, const float* __restrict__ gb,
    float* __restrict__ xbuf, u16* __restrict__ act_out)
{
    __shared__ u16 wlds[KK * 1024];   // 55296 B
    int t = threadIdx.x;
    int wv = t >> 6, l = t & 63;
    int lr = l & 15, lg = l >> 4;

    // cooperative coalesced stage: 3456 uint4
    {
        const uint4* src = (const uint4*)Wp;
        uint4* dst = (uint4*)wlds;
#pragma unroll
        for (int q = 0; q < 7; q++) {
            int e = q * 512 + t;
            if (e < 3456) dst[e] = src[e];
        }
    }
    __syncthreads();

    float g0 = 0.f, b0v = 0.f, g1 = 0.f, b1v = 0.f;
    if (M & 4) { g0 = gb[lr]; b0v = gb[32 + lr]; g1 = gb[16 + lr]; b1v = gb[48 + lr]; }

#pragma unroll
    for (int tile = 0; tile < 2; tile++) {
        int p0 = ((blockIdx.x * 8 + wv) * 2 + tile) * 16;
        int rowaddr = p0 + lr;

        int idx[KK];
#pragma unroll
        for (int k = 0; k < KK; k++) idx[k] = pairs[k * N_PTS + rowaddr];

        uint4 qr[8];
#pragma unroll
        for (int k = 0; k < 8; k++) {
            int ic = idx[k] < 0 ? 0 : idx[k];
            qr[k] = *(const uint4*)(act_in + (long)ic * CC + lg * 8);
        }

        f32x4 acc0 = {0.f, 0.f, 0.f, 0.f}, acc1 = {0.f, 0.f, 0.f, 0.f};
#pragma unroll
        for (int k = 0; k < KK; k++) {
            int s = k & 7;
            uint4 q = qr[s];
            if (k + 8 < KK) {
                int kn = k + 8;
                int ic = idx[kn] < 0 ? 0 : idx[kn];
                qr[s] = *(const uint4*)(act_in + (long)ic * CC + lg * 8);
            }
            u32 msk = idx[k] >= 0 ? 0xFFFFFFFFu : 0u;
            q.x &= msk; q.y &= msk; q.z &= msk; q.w &= msk;
            union { uint4 q; s16x8 v; } a;
            a.q = q;
            const s16x8* wb = (const s16x8*)wlds + k * 128 + l;
            s16x8 w0 = wb[0];
            s16x8 w1 = wb[64];
            acc0 = __builtin_amdgcn_mfma_f32_16x16x32_bf16(a.v, w0, acc0, 0, 0, 0);
            acc1 = __builtin_amdgcn_mfma_f32_16x16x32_bf16(a.v, w1, acc1, 0, 0, 0);
        }
#pragma unroll
        for (int r = 0; r < 4; r++) {
            int row = p0 + lg * 4 + r;
            long o0 = (long)row * 32 + lr, o1 = o0 + 16;
            float v0 = acc0[r], v1 = acc1[r];
            if (M & 1) { v0 += xbuf[o0]; v1 += xbuf[o1]; }
            if (M & 2) { xbuf[o0] = v0; xbuf[o1] = v1; }
            if (M & 4) {
                act_out[o0] = f2bf(fmaxf(fmaf(v0, g0, b0v), 0.f));
                act_out[o1] = f2bf(fmaxf(fmaf(v1, g1, b1v), 0.f));
            }
        }
    }
}

// ---- attention v7: 1 window per 512-thread block, 8-wave roles, 39.4KB LDS ----
#define A5_RIDX 0
#define A5_QSB  4096
#define A5_KSB  6656
#define A5_VST  9216
#define A5_SC   11776
#define A5_BQ   20992
#define A5_BK   30208
#define A5_SIZE 39424

__global__ __launch_bounds__(512, 8) void attn7_kernel(
    const float* __restrict__ x, const int* __restrict__ win_idx,
    const int* __restrict__ rel_idx,
    const u16* __restrict__ wqkvB, const u16* __restrict__ wprojB,
    const float* __restrict__ Pf,
    const u16* __restrict__ tqB, const u16* __restrict__ tkB, const u16* __restrict__ tvb,
    float* __restrict__ out)
{
    __shared__ __align__(16) char arena[A5_SIZE];
    int*   ridx = (int*)(arena + A5_RIDX);
    u16*   qsb  = (u16*)(arena + A5_QSB);
    u16*   ksb  = (u16*)(arena + A5_KSB);
    u16*   vsT  = (u16*)(arena + A5_VST);
    float* sc   = (float*)(arena + A5_SC);
    u16*   psb  = (u16*)(arena + A5_SC);
    u16*   Bq   = (u16*)(arena + A5_BQ);
    u16*   Bk   = (u16*)(arena + A5_BK);
    float* ot   = (float*)(arena + A5_BQ);

    int w = blockIdx.x, t = threadIdx.x;
    int wv = t >> 6, l = t & 63, lr = l & 15, lg = l >> 4;

    if (t < 256) {
        int4 r4 = *(const int4*)(rel_idx + (long)w * 1024 + t * 4);
        *(int4*)(ridx + t * 4) = r4;
    }
    // qkv: 12 MFMA over 8 waves
    {
        const float* bqkv = Pf + 256;
        for (int pi = wv; pi < 12; pi += 8) {
            int n = pi >> 1, m = pi & 1;
            int gi = win_idx[w * 32 + m * 16 + lr];
            const float* xr = x + (long)gi * 32 + lg * 8;
            float4 x0 = *(const float4*)(xr);
            float4 x1 = *(const float4*)(xr + 4);
            union { s16x8 v; u16 h[8]; } a;
            a.h[0] = f2bf(x0.x); a.h[1] = f2bf(x0.y); a.h[2] = f2bf(x0.z); a.h[3] = f2bf(x0.w);
            a.h[4] = f2bf(x1.x); a.h[5] = f2bf(x1.y); a.h[6] = f2bf(x1.z); a.h[7] = f2bf(x1.w);
            s16x8 b = *(const s16x8*)(wqkvB + ((n * 64 + l) << 3));
            f32x4 acc = {0.f, 0.f, 0.f, 0.f};
            acc = __builtin_amdgcn_mfma_f32_16x16x32_bf16(a.v, b, acc, 0, 0, 0);
            int tt = n * 16 + lr;
            float bias = bqkv[tt];
#pragma unroll
            for (int r = 0; r < 4; r++) {
                int tok = m * 16 + lg * 4 + r;
                float v = acc[r] + bias;
                if (tt < 32)      qsb[tok * 40 + tt] = f2bf(v * 0.25f);   // HD^-0.5
                else if (tt < 64) ksb[tok * 40 + (tt - 32)] = f2bf(v);
                else              vsT[(tt - 64) * 40 + tok] = f2bf(v);
            }
        }
    }
    __syncthreads();

    // per-h rel-bias: 8-wave roles (tb, m, n-half), 4-5 MFMA each
    for (int h = 0; h < NH; h++) {
        {
            int tb = (wv >> 2) & 1, m = (wv >> 1) & 1, nh = wv & 1;
            const u16* src = tb ? ksb : qsb;
            const u16* tab = tb ? tkB : tqB;
            u16* dst = tb ? Bk : Bq;
            s16x8 a = {0, 0, 0, 0, 0, 0, 0, 0};
            if (lg < 2) a = *(const s16x8*)(src + (m * 16 + lr) * 40 + h * 16 + lg * 8);
            int n0 = nh * 5, n1 = nh ? 9 : 5;
            for (int n = n0; n < n1; n++) {
                s16x8 b = *(const s16x8*)(tab + (((h * 9 + n) * 64 + l) << 3));
                f32x4 acc = {0.f, 0.f, 0.f, 0.f};
                acc = __builtin_amdgcn_mfma_f32_16x16x32_bf16(a, b, acc, 0, 0, 0);
#pragma unroll
                for (int r = 0; r < 4; r++)
                    dst[(m * 16 + lg * 4 + r) * 144 + n * 16 + lr] = f2bf(acc[r]);
            }
        }
        __syncthreads();
        for (int e = t; e < 1024; e += 512) {
            int i = e >> 5, j = e & 31, r = ridx[e];
            sc[h * 1152 + i * 36 + j] = bf2f(Bq[i * 144 + r]) + bf2f(Bk[j * 144 + r]);
        }
        __syncthreads();
    }

    // qk^T: 8 MFMA, exactly one per wave
    {
        int h = wv >> 2, m = (wv >> 1) & 1, n = wv & 1;
        s16x8 a = {0, 0, 0, 0, 0, 0, 0, 0}, b = {0, 0, 0, 0, 0, 0, 0, 0};
        if (lg < 2) {
            a = *(const s16x8*)(qsb + (m * 16 + lr) * 40 + h * 16 + lg * 8);
            b = *(const s16x8*)(ksb + (n * 16 + lr) * 40 + h * 16 + lg * 8);
        }
        f32x4 acc = {0.f, 0.f, 0.f, 0.f};
        acc = __builtin_amdgcn_mfma_f32_16x16x32_bf16(a, b, acc, 0, 0, 0);
#pragma unroll
        for (int r = 0; r < 4; r++)
            sc[h * 1152 + (m * 16 + lg * 4 + r) * 36 + n * 16 + lr] += acc[r];
    }
    __syncthreads();

    // softmax: 8 lanes per row (64 rows), 4 elems each
    {
        int rr = t >> 3, sub = t & 7;
        int h = rr >> 5, i = rr & 31, j0 = sub * 4;
        const float* srow = sc + h * 1152 + i * 36 + j0;
        float pv[4];
        float m_ = -1e30f;
#pragma unroll
        for (int jj = 0; jj < 4; jj++) { pv[jj] = srow[jj]; m_ = fmaxf(m_, pv[jj]); }
        m_ = fmaxf(m_, __shfl_xor(m_, 1));
        m_ = fmaxf(m_, __shfl_xor(m_, 2));
        m_ = fmaxf(m_, __shfl_xor(m_, 4));
        float sum = 0.f;
#pragma unroll
        for (int jj = 0; jj < 4; jj++) { pv[jj] = __expf(pv[jj] - m_); sum += pv[jj]; }
        sum += __shfl_xor(sum, 1);
        sum += __shfl_xor(sum, 2);
        sum += __shfl_xor(sum, 4);
        float inv = 1.f / sum;
        __syncthreads();   // all sc reads complete before psb alias overwrite
        u16* prow = psb + h * 1280 + i * 40 + j0;
#pragma unroll
        for (int jj = 0; jj < 4; jj++) prow[jj] = f2bf(pv[jj] * inv);
    }
    __syncthreads();

    // tv gather: one (i,hp) per thread
    {
        int i = t >> 4, hp = t & 15, h = hp >> 3;
        const u16* prow = psb + h * 1280 + i * 40;
        const int* rrow = ridx + i * 32;
        float a0 = 0.f, a1 = 0.f;
#pragma unroll 8
        for (int j = 0; j < CAP; j++) {
            int r = rrow[j];
            float p = bf2f(prow[j]);
            u32 tv2 = *(const u32*)(tvb + r * 32 + hp * 2);
            a0 = fmaf(p, __uint_as_float(tv2 << 16), a0);
            a1 = fmaf(p, __uint_as_float(tv2 & 0xffff0000u), a1);
        }
        ot[i * 36 + hp * 2] = a0;
        ot[i * 36 + hp * 2 + 1] = a1;
    }
    __syncthreads();

    // PV: 4 MFMA (waves 0-3), accumulate into ot
    if (wv < 4) {
        int h = wv >> 1, m = wv & 1;
        s16x8 a = *(const s16x8*)(psb + h * 1280 + (m * 16 + lr) * 40 + lg * 8);
        s16x8 b = *(const s16x8*)(vsT + (h * 16 + lr) * 40 + lg * 8);
        f32x4 acc = {0.f, 0.f, 0.f, 0.f};
        acc = __builtin_amdgcn_mfma_f32_16x16x32_bf16(a, b, acc, 0, 0, 0);
#pragma unroll
        for (int r = 0; r < 4; r++)
            ot[(m * 16 + lg * 4 + r) * 36 + h * 16 + lr] += acc[r];
    }
    __syncthreads();

    // proj: 4 MFMA (waves 4-7) + residual + scatter
    if (wv >= 4) {
        int m = (wv >> 1) & 1, n = wv & 1;
        union { s16x8 v; u16 h[8]; } a;
        const float* orow = ot + (m * 16 + lr) * 36 + lg * 8;
#pragma unroll
        for (int e = 0; e < 8; e++) a.h[e] = f2bf(orow[e]);
        s16x8 b = *(const s16x8*)(wprojB + ((n * 64 + l) << 3));
        f32x4 acc = {0.f, 0.f, 0.f, 0.f};
        acc = __builtin_amdgcn_mfma_f32_16x16x32_bf16(a.v, b, acc, 0, 0, 0);
        int c = n * 16 + lr;
        float bb = Pf[352 + c];
#pragma unroll
        for (int r = 0; r < 4; r++) {
            int tok = m * 16 + lg * 4 + r;
            int gi = win_idx[w * 32 + tok];
            out[(long)gi * 32 + c] = x[(long)gi * 32 + c] + bb + acc[r];
        }
    }
}

// ---- ws byte offsets ----
#define B_PF     0
#define B_ACTA   2048
#define B_ACTB   4196352
#define B_FEATS  8390656
#define B_WA1    8914944
#define B_WA2    8970240
#define B_WB1    9025536
#define B_WB2    9080832
#define B_WIN    9136128
#define B_WQKVB  9144320
#define B_WPROJB 9150464
#define B_TQBF   9152512
#define B_TKBF   9170944
#define B_TVBF   9189376

extern "C" void kernel_launch(void* const* d_in, const int* in_sizes, int n_in,
                              void* d_out, int out_size, void* d_ws, size_t ws_size,
                              hipStream_t stream) {
    const int* pairs   = (const int*)d_in[1];
    const int* win_idx = (const int*)d_in[2];
    const int* rel_idx = (const int*)d_in[3];

    char* wsb = (char*)d_ws;
    float* Pf = (float*)(wsb + B_PF);
    u16* actA = (u16*)(wsb + B_ACTA);
    u16* actB = (u16*)(wsb + B_ACTB);
    u16* fbf  = (u16*)(wsb + B_FEATS);
    u16* WpA1 = (u16*)(wsb + B_WA1);
    u16* WpA2 = (u16*)(wsb + B_WA2);
    u16* WpB1 = (u16*)(wsb + B_WB1);
    u16* WpB2 = (u16*)(wsb + B_WB2);
    u16* WpIN = (u16*)(wsb + B_WIN);
    u16* wqkvB  = (u16*)(wsb + B_WQKVB);
    u16* wprojB = (u16*)(wsb + B_WPROJB);
    u16* tqB = (u16*)(wsb + B_TQBF);
    u16* tkB = (u16*)(wsb + B_TKBF);
    u16* tvb = (u16*)(wsb + B_TVBF);
    float* X  = (float*)d_out;

    Ptrs pp;
    for (int i = 0; i < 24; i++) pp.p[i] = d_in[i];
    prep_all<<<dim3(1024, 9), 256, 0, stream>>>(pp, fbf,
                                                WpA1, WpA2, WpB1, WpB2, WpIN,
                                                wqkvB, wprojB, tqB, tkB, tvb, Pf);

    convin_mfma<<<1024, 256, 0, stream>>>(fbf, pairs, WpIN, Pf + 0, X, actA);
    conv32_lds<4><<<256, 512, 0, stream>>>(actA, pairs, WpA1, Pf + 64,  X, actB);
    conv32_lds<7><<<256, 512, 0, stream>>>(actB, pairs, WpA2, Pf + 128, X, actA);
    conv32_lds<4><<<256, 512, 0, stream>>>(actA, pairs, WpB1, Pf + 192, X, actB);
    conv32_lds<3><<<256, 512, 0, stream>>>(actB, pairs, WpB2, Pf, X, actA);

    attn7_kernel<<<NWIN, 512, 0, stream>>>(X, win_idx, rel_idx,
                                           wqkvB, wprojB, Pf,
                                           tqB, tkB, tvb, X);
}

// Round 14
// 109.376 us; speedup vs baseline: 1.3631x; 1.0227x over previous
//
#include <hip/hip_runtime.h>

typedef unsigned short u16;
typedef unsigned int u32;

#define N_PTS 65536
#define KK 27
#define CIN 4
#define CC 32
#define NWIN 2048
#define CAP 32
#define NH 2
#define HD 16

typedef short s16x8 __attribute__((ext_vector_type(8)));
typedef float f32x4 __attribute__((ext_vector_type(4)));

__device__ __forceinline__ float bf2f(u16 h) { return __uint_as_float(((u32)h) << 16); }
__device__ __forceinline__ u16 f2bf(float f) {
    u32 u = __float_as_uint(f);
    u32 r = (u + 0x7FFFu + ((u >> 16) & 1u)) >> 16;
    return (u16)r;
}
__device__ __forceinline__ float ldany(const void* src, int i, bool isbf) {
    return isbf ? bf2f(((const u16*)src)[i]) : ((const float*)src)[i];
}
__device__ __forceinline__ u16 ldbf(const void* src, int i, bool isbf) {
    return isbf ? ((const u16*)src)[i] : f2bf(((const float*)src)[i]);
}

// ---- single prep kernel; per-block inline dtype detection; grid-stride segs ----
#define PREP_BX 128
struct Ptrs { const void* p[24]; };

__global__ __launch_bounds__(256) void prep_all(
    Ptrs in,
    u16* __restrict__ fbf,
    u16* __restrict__ WpA1, u16* __restrict__ WpA2,
    u16* __restrict__ WpB1, u16* __restrict__ WpB2, u16* __restrict__ WpIN,
    u16* __restrict__ wqkvB, u16* __restrict__ wprojB,
    u16* __restrict__ tqB, u16* __restrict__ tkB, u16* __restrict__ tvb,
    float* __restrict__ Pf)
{
    __shared__ int red[256];
    int t = threadIdx.x;
    {
        u32 wd = ((const u32*)in.p[0])[t];
        u32 e = (wd >> 7) & 0xFFu;
        red[t] = (e >= 100 && e <= 140) ? 1 : 0;
    }
    __syncthreads();
    for (int s = 128; s > 0; s >>= 1) {
        if (t < s) red[t] += red[t + s];
        __syncthreads();
    }
    bool isbf = red[0] > 128;

    int seg = blockIdx.y;
    const int STR = PREP_BX * 256;
    if (seg == 0) {
        for (int i = blockIdx.x * 256 + t; i < N_PTS * CIN; i += STR)
            fbf[i] = ldbf(in.p[0], i, isbf);
        return;
    }
    if (seg <= 4) {
        const void* src = in.p[seg == 1 ? 7 : seg == 2 ? 10 : seg == 3 ? 13 : 16];
        u16* dst = seg == 1 ? WpA1 : seg == 2 ? WpA2 : seg == 3 ? WpB1 : WpB2;
        for (int i = blockIdx.x * 256 + t; i < 27648; i += STR) {
            int e = i & 7, l = (i >> 3) & 63, dt = (i >> 9) & 1, k = i >> 10;
            dst[i] = ldbf(src, k * 1024 + ((l >> 4) * 8 + e) * 32 + dt * 16 + (l & 15), isbf);
        }
        return;
    }
    if (seg == 5) {
        for (int i = blockIdx.x * 256 + t; i < 4096; i += STR) {
            int e = i & 7, l = (i >> 3) & 63, dt = (i >> 9) & 1, kk = i >> 10;
            int g = kk * 32 + (l >> 4) * 8 + e;
            int tp = g >> 2, c = g & 3;
            WpIN[i] = (tp < KK) ? ldbf(in.p[4], tp * 128 + c * 32 + dt * 16 + (l & 15), isbf) : (u16)0;
        }
        return;
    }
    if (seg == 6) {
        for (int i = blockIdx.x * 256 + t; i < 4096; i += STR) {
            if (i < 3072) {
                int e = i & 7, l = (i >> 3) & 63, n = i >> 9;
                wqkvB[i] = ldbf(in.p[17], ((l >> 4) * 8 + e) * 96 + n * 16 + (l & 15), isbf);
            } else {
                int o2 = i - 3072;
                int e = o2 & 7, l = (o2 >> 3) & 63, n = o2 >> 9;
                wprojB[o2] = ldbf(in.p[19], ((l >> 4) * 8 + e) * 32 + n * 16 + (l & 15), isbf);
            }
        }
        return;
    }
    if (seg == 7) {
        for (int i = blockIdx.x * 256 + t; i < 23040; i += STR) {
            if (i < 9216) {
                int e = i & 7, l = (i >> 3) & 63, nn = i >> 9;
                int n = nn % 9, h = nn / 9, lr = l & 15, lg = l >> 4;
                int k = lg * 8 + e;
                tqB[i] = (k < HD) ? ldbf(in.p[21], (n * 16 + lr) * 32 + h * 16 + k, isbf) : (u16)0;
            } else if (i < 18432) {
                int o2 = i - 9216;
                int e = o2 & 7, l = (o2 >> 3) & 63, nn = o2 >> 9;
                int n = nn % 9, h = nn / 9, lr = l & 15, lg = l >> 4;
                int k = lg * 8 + e;
                tkB[o2] = (k < HD) ? ldbf(in.p[22], (n * 16 + lr) * 32 + h * 16 + k, isbf) : (u16)0;
            } else {
                int o2 = i - 18432;
                tvb[o2] = ldbf(in.p[23], o2, isbf);
            }
        }
        return;
    }
    // seg 8: GB(8x32) | bqkv(96)@256 | bproj(32)@352
    {
        int i = blockIdx.x * 256 + t;
        if (i < 256) {
            const int srcs[8] = {5, 6, 8, 9, 11, 12, 14, 15};
            Pf[i] = ldany(in.p[srcs[i >> 5]], i & 31, isbf);
        } else if (i < 352) {
            Pf[i] = ldany(in.p[18], i - 256, isbf);
        } else if (i < 384) {
            Pf[i] = ldany(in.p[20], i - 352, isbf);
        }
    }
}

// ---- MFMA input conv: batch-load phase then compute phase ----
__global__ __launch_bounds__(256) void convin_mfma(
    const u16* __restrict__ fb, const int* __restrict__ pairs,
    const u16* __restrict__ Wp, const float* __restrict__ gb,
    float* __restrict__ xbuf, u16* __restrict__ act_out)
{
    int t = threadIdx.x;
    int wv = t >> 6, l = t & 63;
    int lr = l & 15, lg = l >> 4;
    int p0 = (blockIdx.x * 4 + wv) * 16;
    int rowaddr = p0 + lr;

    int ia[4], ib[4];
    u32 ma[4], mb[4];
#pragma unroll
    for (int kk = 0; kk < 4; kk++) {
        int t0 = kk * 8 + lg * 2;
        int ta = t0 < 26 ? t0 : 26;
        int tb = (t0 + 1) < 26 ? (t0 + 1) : 26;
        ia[kk] = pairs[ta * N_PTS + rowaddr];
        ib[kk] = pairs[tb * N_PTS + rowaddr];
        ma[kk] = (t0 < KK && ia[kk] >= 0) ? 0xFFFFFFFFu : 0u;
        mb[kk] = (t0 + 1 < KK && ib[kk] >= 0) ? 0xFFFFFFFFu : 0u;
    }
    uint2 qa[4], qb[4];
    s16x8 b0[4], b1[4];
#pragma unroll
    for (int kk = 0; kk < 4; kk++) {
        qa[kk] = *(const uint2*)(fb + (long)(ia[kk] < 0 ? 0 : ia[kk]) * CIN);
        qb[kk] = *(const uint2*)(fb + (long)(ib[kk] < 0 ? 0 : ib[kk]) * CIN);
        const s16x8* wb = (const s16x8*)Wp + kk * 128 + l;
        b0[kk] = wb[0];
        b1[kk] = wb[64];
    }

    f32x4 acc0 = {0.f, 0.f, 0.f, 0.f}, acc1 = {0.f, 0.f, 0.f, 0.f};
#pragma unroll
    for (int kk = 0; kk < 4; kk++) {
        union { uint4 q; s16x8 v; } a;
        a.q = make_uint4(qa[kk].x & ma[kk], qa[kk].y & ma[kk],
                         qb[kk].x & mb[kk], qb[kk].y & mb[kk]);
        acc0 = __builtin_amdgcn_mfma_f32_16x16x32_bf16(a.v, b0[kk], acc0, 0, 0, 0);
        acc1 = __builtin_amdgcn_mfma_f32_16x16x32_bf16(a.v, b1[kk], acc1, 0, 0, 0);
    }
    float g0 = gb[lr], b0v = gb[32 + lr], g1 = gb[16 + lr], b1v = gb[48 + lr];
#pragma unroll
    for (int r = 0; r < 4; r++) {
        int row = p0 + lg * 4 + r;
        long o0 = (long)row * 32 + lr, o1 = o0 + 16;
        float v0 = acc0[r], v1 = acc1[r];
        xbuf[o0] = v0; xbuf[o1] = v1;
        act_out[o0] = f2bf(fmaxf(fmaf(v0, g0, b0v), 0.f));
        act_out[o1] = f2bf(fmaxf(fmaf(v1, g1, b1v), 0.f));
    }
}

// ---- MFMA 32->32 gather conv; 27 taps in LDS; 1 tile/wave, grid 512 ----
// 512 blocks / 256 CU -> 2 blocks/CU co-resident (110KB LDS) = 4 waves/SIMD.
// M: bit0 READ_X, bit1 WRITE_X, bit2 WRITE_ACT
template <int M>
__global__ __launch_bounds__(512, 4) void conv32_lds(
    const u16* __restrict__ act_in, const int* __restrict__ pairs,
    const u16* __restrict__ Wp, const float* __restrict__ gb,
    float* __restrict__ xbuf, u16* __restrict__ act_out)
{
    __shared__ u16 wlds[KK * 1024];   // 55296 B
    int t = threadIdx.x;
    int wv = t >> 6, l = t & 63;
    int lr = l & 15, lg = l >> 4;

    // cooperative coalesced stage: 3456 uint4
    {
        const uint4* src = (const uint4*)Wp;
        uint4* dst = (uint4*)wlds;
#pragma unroll
        for (int q = 0; q < 7; q++) {
            int e = q * 512 + t;
            if (e < 3456) dst[e] = src[e];
        }
    }
    __syncthreads();

    float g0 = 0.f, b0v = 0.f, g1 = 0.f, b1v = 0.f;
    if (M & 4) { g0 = gb[lr]; b0v = gb[32 + lr]; g1 = gb[16 + lr]; b1v = gb[48 + lr]; }

    int p0 = (blockIdx.x * 8 + wv) * 16;
    int rowaddr = p0 + lr;

    int idx[KK];
#pragma unroll
    for (int k = 0; k < KK; k++) idx[k] = pairs[k * N_PTS + rowaddr];

    uint4 qr[8];
#pragma unroll
    for (int k = 0; k < 8; k++) {
        int ic = idx[k] < 0 ? 0 : idx[k];
        qr[k] = *(const uint4*)(act_in + (long)ic * CC + lg * 8);
    }

    f32x4 acc0 = {0.f, 0.f, 0.f, 0.f}, acc1 = {0.f, 0.f, 0.f, 0.f};
#pragma unroll
    for (int k = 0; k < KK; k++) {
        int s = k & 7;
        uint4 q = qr[s];
        if (k + 8 < KK) {
            int kn = k + 8;
            int ic = idx[kn] < 0 ? 0 : idx[kn];
            qr[s] = *(const uint4*)(act_in + (long)ic * CC + lg * 8);
        }
        u32 msk = idx[k] >= 0 ? 0xFFFFFFFFu : 0u;
        q.x &= msk; q.y &= msk; q.z &= msk; q.w &= msk;
        union { uint4 q; s16x8 v; } a;
        a.q = q;
        const s16x8* wb = (const s16x8*)wlds + k * 128 + l;
        s16x8 w0 = wb[0];
        s16x8 w1 = wb[64];
        acc0 = __builtin_amdgcn_mfma_f32_16x16x32_bf16(a.v, w0, acc0, 0, 0, 0);
        acc1 = __builtin_amdgcn_mfma_f32_16x16x32_bf16(a.v, w1, acc1, 0, 0, 0);
    }
#pragma unroll
    for (int r = 0; r < 4; r++) {
        int row = p0 + lg * 4 + r;
        long o0 = (long)row * 32 + lr, o1 = o0 + 16;
        float v0 = acc0[r], v1 = acc1[r];
        if (M & 1) { v0 += xbuf[o0]; v1 += xbuf[o1]; }
        if (M & 2) { xbuf[o0] = v0; xbuf[o1] = v1; }
        if (M & 4) {
            act_out[o0] = f2bf(fmaxf(fmaf(v0, g0, b0v), 0.f));
            act_out[o1] = f2bf(fmaxf(fmaf(v1, g1, b1v), 0.f));
        }
    }
}

// ---- attention v7: 1 window per 512-thread block, 8-wave roles, 39.4KB LDS ----
#define A5_RIDX 0
#define A5_QSB  4096
#define A5_KSB  6656
#define A5_VST  9216
#define A5_SC   11776
#define A5_BQ   20992
#define A5_BK   30208
#define A5_SIZE 39424

__global__ __launch_bounds__(512, 8) void attn7_kernel(
    const float* __restrict__ x, const int* __restrict__ win_idx,
    const int* __restrict__ rel_idx,
    const u16* __restrict__ wqkvB, const u16* __restrict__ wprojB,
    const float* __restrict__ Pf,
    const u16* __restrict__ tqB, const u16* __restrict__ tkB, const u16* __restrict__ tvb,
    float* __restrict__ out)
{
    __shared__ __align__(16) char arena[A5_SIZE];
    int*   ridx = (int*)(arena + A5_RIDX);
    u16*   qsb  = (u16*)(arena + A5_QSB);
    u16*   ksb  = (u16*)(arena + A5_KSB);
    u16*   vsT  = (u16*)(arena + A5_VST);
    float* sc   = (float*)(arena + A5_SC);
    u16*   psb  = (u16*)(arena + A5_SC);
    u16*   Bq   = (u16*)(arena + A5_BQ);
    u16*   Bk   = (u16*)(arena + A5_BK);
    float* ot   = (float*)(arena + A5_BQ);

    int w = blockIdx.x, t = threadIdx.x;
    int wv = t >> 6, l = t & 63, lr = l & 15, lg = l >> 4;

    if (t < 256) {
        int4 r4 = *(const int4*)(rel_idx + (long)w * 1024 + t * 4);
        *(int4*)(ridx + t * 4) = r4;
    }
    // qkv: 12 MFMA over 8 waves
    {
        const float* bqkv = Pf + 256;
        for (int pi = wv; pi < 12; pi += 8) {
            int n = pi >> 1, m = pi & 1;
            int gi = win_idx[w * 32 + m * 16 + lr];
            const float* xr = x + (long)gi * 32 + lg * 8;
            float4 x0 = *(const float4*)(xr);
            float4 x1 = *(const float4*)(xr + 4);
            union { s16x8 v; u16 h[8]; } a;
            a.h[0] = f2bf(x0.x); a.h[1] = f2bf(x0.y); a.h[2] = f2bf(x0.z); a.h[3] = f2bf(x0.w);
            a.h[4] = f2bf(x1.x); a.h[5] = f2bf(x1.y); a.h[6] = f2bf(x1.z); a.h[7] = f2bf(x1.w);
            s16x8 b = *(const s16x8*)(wqkvB + ((n * 64 + l) << 3));
            f32x4 acc = {0.f, 0.f, 0.f, 0.f};
            acc = __builtin_amdgcn_mfma_f32_16x16x32_bf16(a.v, b, acc, 0, 0, 0);
            int tt = n * 16 + lr;
            float bias = bqkv[tt];
#pragma unroll
            for (int r = 0; r < 4; r++) {
                int tok = m * 16 + lg * 4 + r;
                float v = acc[r] + bias;
                if (tt < 32)      qsb[tok * 40 + tt] = f2bf(v * 0.25f);   // HD^-0.5
                else if (tt < 64) ksb[tok * 40 + (tt - 32)] = f2bf(v);
                else              vsT[(tt - 64) * 40 + tok] = f2bf(v);
            }
        }
    }
    __syncthreads();

    // per-h rel-bias: 8-wave roles (tb, m, n-half), 4-5 MFMA each
    for (int h = 0; h < NH; h++) {
        {
            int tb = (wv >> 2) & 1, m = (wv >> 1) & 1, nh = wv & 1;
            const u16* src = tb ? ksb : qsb;
            const u16* tab = tb ? tkB : tqB;
            u16* dst = tb ? Bk : Bq;
            s16x8 a = {0, 0, 0, 0, 0, 0, 0, 0};
            if (lg < 2) a = *(const s16x8*)(src + (m * 16 + lr) * 40 + h * 16 + lg * 8);
            int n0 = nh * 5, n1 = nh ? 9 : 5;
            for (int n = n0; n < n1; n++) {
                s16x8 b = *(const s16x8*)(tab + (((h * 9 + n) * 64 + l) << 3));
                f32x4 acc = {0.f, 0.f, 0.f, 0.f};
                acc = __builtin_amdgcn_mfma_f32_16x16x32_bf16(a, b, acc, 0, 0, 0);
#pragma unroll
                for (int r = 0; r < 4; r++)
                    dst[(m * 16 + lg * 4 + r) * 144 + n * 16 + lr] = f2bf(acc[r]);
            }
        }
        __syncthreads();
        for (int e = t; e < 1024; e += 512) {
            int i = e >> 5, j = e & 31, r = ridx[e];
            sc[h * 1152 + i * 36 + j] = bf2f(Bq[i * 144 + r]) + bf2f(Bk[j * 144 + r]);
        }
        __syncthreads();
    }

    // qk^T: 8 MFMA, exactly one per wave
    {
        int h = wv >> 2, m = (wv >> 1) & 1, n = wv & 1;
        s16x8 a = {0, 0, 0, 0, 0, 0, 0, 0}, b = {0, 0, 0, 0, 0, 0, 0, 0};
        if (lg < 2) {
            a = *(const s16x8*)(qsb + (m * 16 + lr) * 40 + h * 16 + lg * 8);
            b = *(const s16x8*)(ksb + (n * 16 + lr) * 40 + h * 16 + lg * 8);
        }
        f32x4 acc = {0.f, 0.f, 0.f, 0.f};
        acc = __builtin_amdgcn_mfma_f32_16x16x32_bf16(a, b, acc, 0, 0, 0);
#pragma unroll
        for (int r = 0; r < 4; r++)
            sc[h * 1152 + (m * 16 + lg * 4 + r) * 36 + n * 16 + lr] += acc[r];
    }
    __syncthreads();

    // softmax: 8 lanes per row (64 rows), 4 elems each
    {
        int rr = t >> 3, sub = t & 7;
        int h = rr >> 5, i = rr & 31, j0 = sub * 4;
        const float* srow = sc + h * 1152 + i * 36 + j0;
        float pv[4];
        float m_ = -1e30f;
#pragma unroll
        for (int jj = 0; jj < 4; jj++) { pv[jj] = srow[jj]; m_ = fmaxf(m_, pv[jj]); }
        m_ = fmaxf(m_, __shfl_xor(m_, 1));
        m_ = fmaxf(m_, __shfl_xor(m_, 2));
        m_ = fmaxf(m_, __shfl_xor(m_, 4));
        float sum = 0.f;
#pragma unroll
        for (int jj = 0; jj < 4; jj++) { pv[jj] = __expf(pv[jj] - m_); sum += pv[jj]; }
        sum += __shfl_xor(sum, 1);
        sum += __shfl_xor(sum, 2);
        sum += __shfl_xor(sum, 4);
        float inv = 1.f / sum;
        __syncthreads();   // all sc reads complete before psb alias overwrite
        u16* prow = psb + h * 1280 + i * 40 + j0;
#pragma unroll
        for (int jj = 0; jj < 4; jj++) prow[jj] = f2bf(pv[jj] * inv);
    }
    __syncthreads();

    // tv gather: one (i,hp) per thread
    {
        int i = t >> 4, hp = t & 15, h = hp >> 3;
        const u16* prow = psb + h * 1280 + i * 40;
        const int* rrow = ridx + i * 32;
        float a0 = 0.f, a1 = 0.f;
#pragma unroll 8
        for (int j = 0; j < CAP; j++) {
            int r = rrow[j];
            float p = bf2f(prow[j]);
            u32 tv2 = *(const u32*)(tvb + r * 32 + hp * 2);
            a0 = fmaf(p, __uint_as_float(tv2 << 16), a0);
            a1 = fmaf(p, __uint_as_float(tv2 & 0xffff0000u), a1);
        }
        ot[i * 36 + hp * 2] = a0;
        ot[i * 36 + hp * 2 + 1] = a1;
    }
    __syncthreads();

    // PV: 4 MFMA (waves 0-3), accumulate into ot
    if (wv < 4) {
        int h = wv >> 1, m = wv & 1;
        s16x8 a = *(const s16x8*)(psb + h * 1280 + (m * 16 + lr) * 40 + lg * 8);
        s16x8 b = *(const s16x8*)(vsT + (h * 16 + lr) * 40 + lg * 8);
        f32x4 acc = {0.f, 0.f, 0.f, 0.f};
        acc = __builtin_amdgcn_mfma_f32_16x16x32_bf16(a, b, acc, 0, 0, 0);
#pragma unroll
        for (int r = 0; r < 4; r++)
            ot[(m * 16 + lg * 4 + r) * 36 + h * 16 + lr] += acc[r];
    }
    __syncthreads();

    // proj: 4 MFMA (waves 4-7) + residual + scatter
    if (wv >= 4) {
        int m = (wv >> 1) & 1, n = wv & 1;
        union { s16x8 v; u16 h[8]; } a;
        const float* orow = ot + (m * 16 + lr) * 36 + lg * 8;
#pragma unroll
        for (int e = 0; e < 8; e++) a.h[e] = f2bf(orow[e]);
        s16x8 b = *(const s16x8*)(wprojB + ((n * 64 + l) << 3));
        f32x4 acc = {0.f, 0.f, 0.f, 0.f};
        acc = __builtin_amdgcn_mfma_f32_16x16x32_bf16(a.v, b, acc, 0, 0, 0);
        int c = n * 16 + lr;
        float bb = Pf[352 + c];
#pragma unroll
        for (int r = 0; r < 4; r++) {
            int tok = m * 16 + lg * 4 + r;
            int gi = win_idx[w * 32 + tok];
            out[(long)gi * 32 + c] = x[(long)gi * 32 + c] + bb + acc[r];
        }
    }
}

// ---- ws byte offsets ----
#define B_PF     0
#define B_ACTA   2048
#define B_ACTB   4196352
#define B_FEATS  8390656
#define B_WA1    8914944
#define B_WA2    8970240
#define B_WB1    9025536
#define B_WB2    9080832
#define B_WIN    9136128
#define B_WQKVB  9144320
#define B_WPROJB 9150464
#define B_TQBF   9152512
#define B_TKBF   9170944
#define B_TVBF   9189376

extern "C" void kernel_launch(void* const* d_in, const int* in_sizes, int n_in,
                              void* d_out, int out_size, void* d_ws, size_t ws_size,
                              hipStream_t stream) {
    const int* pairs   = (const int*)d_in[1];
    const int* win_idx = (const int*)d_in[2];
    const int* rel_idx = (const int*)d_in[3];

    char* wsb = (char*)d_ws;
    float* Pf = (float*)(wsb + B_PF);
    u16* actA = (u16*)(wsb + B_ACTA);
    u16* actB = (u16*)(wsb + B_ACTB);
    u16* fbf  = (u16*)(wsb + B_FEATS);
    u16* WpA1 = (u16*)(wsb + B_WA1);
    u16* WpA2 = (u16*)(wsb + B_WA2);
    u16* WpB1 = (u16*)(wsb + B_WB1);
    u16* WpB2 = (u16*)(wsb + B_WB2);
    u16* WpIN = (u16*)(wsb + B_WIN);
    u16* wqkvB  = (u16*)(wsb + B_WQKVB);
    u16* wprojB = (u16*)(wsb + B_WPROJB);
    u16* tqB = (u16*)(wsb + B_TQBF);
    u16* tkB = (u16*)(wsb + B_TKBF);
    u16* tvb = (u16*)(wsb + B_TVBF);
    float* X  = (float*)d_out;

    Ptrs pp;
    for (int i = 0; i < 24; i++) pp.p[i] = d_in[i];
    prep_all<<<dim3(PREP_BX, 9), 256, 0, stream>>>(pp, fbf,
                                                   WpA1, WpA2, WpB1, WpB2, WpIN,
                                                   wqkvB, wprojB, tqB, tkB, tvb, Pf);

    convin_mfma<<<1024, 256, 0, stream>>>(fbf, pairs, WpIN, Pf + 0, X, actA);
    conv32_lds<4><<<512, 512, 0, stream>>>(actA, pairs, WpA1, Pf + 64,  X, actB);
    conv32_lds<7><<<512, 512, 0, stream>>>(actB, pairs, WpA2, Pf + 128, X, actA);
    conv32_lds<4><<<512, 512, 0, stream>>>(actA, pairs, WpB1, Pf + 192, X, actB);
    conv32_lds<3><<<512, 512, 0, stream>>>(actB, pairs, WpB2, Pf, X, actA);

    attn7_kernel<<<NWIN, 512, 0, stream>>>(X, win_idx, rel_idx,
                                           wqkvB, wprojB, Pf,
                                           tqB, tkB, tvb, X);
}